// Round 10
// baseline (541.587 us; speedup 1.0000x reference)
//
#include <hip/hip_runtime.h>
#include <hip/hip_bf16.h>

#define N_NODES 100000
#define N_EDGES 3200000
#define DFEAT 256
#define UNITS 256

#define CHUNK 512
#define CHUNK_SHIFT 9
#define NCHUNKS ((N_NODES + CHUNK - 1) / CHUNK)   // 196

#define BIN_TILE 2048
#define BIN_NWG ((N_EDGES + BIN_TILE - 1) / BIN_TILE)   // 1563
#define PADC 208                                  // padded chunk stride in hist_all

typedef short bf16x8 __attribute__((ext_vector_type(8)));
typedef float f32x4 __attribute__((ext_vector_type(4)));

// RNE float -> bf16 bits
__device__ __forceinline__ unsigned short f2bf(float f) {
    union { float f; unsigned u; } v; v.f = f;
    unsigned u = v.u;
    u += 0x7FFFu + ((u >> 16) & 1u);
    return (unsigned short)(u >> 16);
}

// ---------------------------------------------------------------------------
// Merged prelude: blocks [0,25000) convert x fp32->bf16 (1 float4/thr);
// [25000,25256) transpose-convert W; [25256,26819) = chunk_hist.
// ---------------------------------------------------------------------------
__global__ __launch_bounds__(256) void convert_hist(const float4* __restrict__ x4,
                                                    unsigned short* __restrict__ xh,
                                                    const float* __restrict__ w,
                                                    unsigned short* __restrict__ wt,
                                                    const int* __restrict__ erow,
                                                    int* __restrict__ hist_all) {
    if (blockIdx.x < 25000) {
        size_t i = (size_t)blockIdx.x * 256 + threadIdx.x;   // 6.4M float4s
        float4 v = x4[i];
        ushort4 o = make_ushort4(f2bf(v.x), f2bf(v.y), f2bf(v.z), f2bf(v.w));
        *(ushort4*)&xh[i * 4] = o;
    } else if (blockIdx.x < 25256) {
        int n = blockIdx.x - 25000, k = threadIdx.x;
        wt[n * DFEAT + k] = f2bf(w[k * UNITS + n]);
    } else {
        __shared__ int h[256];
        const int wg = blockIdx.x - 25256;
        const int tid = threadIdx.x;
        h[tid] = 0;
        __syncthreads();
        const int base = wg * BIN_TILE;
#pragma unroll
        for (int j = 0; j < 8; ++j) {
            int e = base + j * 256 + tid;
            if (e < N_EDGES) atomicAdd(&h[erow[e] >> CHUNK_SHIFT], 1);
        }
        __syncthreads();
        if (tid < NCHUNKS) hist_all[wg * PADC + tid] = h[tid];
    }
}

// ---------------------------------------------------------------------------
// CSR build — round-3 measured-best structure.
// ---------------------------------------------------------------------------
__global__ __launch_bounds__(256) void col_scan(int* __restrict__ hist_all,
                                                int* __restrict__ chunk_cnt) {
    __shared__ int t[256];
    const int b = blockIdx.x;
    const int tid = threadIdx.x;
    int v[7]; int local = 0;
#pragma unroll
    for (int j = 0; j < 7; ++j) {
        int w = tid * 7 + j;
        v[j] = (w < BIN_NWG) ? hist_all[w * PADC + b] : 0;
        local += v[j];
    }
    t[tid] = local;
    __syncthreads();
    for (int off = 1; off < 256; off <<= 1) {
        int u = 0;
        if (tid >= off) u = t[tid - off];
        __syncthreads();
        if (tid >= off) t[tid] += u;
        __syncthreads();
    }
    int run = t[tid] - local;
#pragma unroll
    for (int j = 0; j < 7; ++j) {
        int w = tid * 7 + j;
        if (w < BIN_NWG) { hist_all[w * PADC + b] = run; run += v[j]; }
    }
    if (tid == 255) chunk_cnt[b] = t[255];
}

__global__ void scan_chunks(const int* __restrict__ chunk_cnt, int* __restrict__ csum) {
    __shared__ int t[256];
    const int tid = threadIdx.x;
    int v = (tid < NCHUNKS) ? chunk_cnt[tid] : 0;
    t[tid] = v;
    __syncthreads();
    for (int off = 1; off < 256; off <<= 1) {
        int u = 0;
        if (tid >= off) u = t[tid - off];
        __syncthreads();
        if (tid >= off) t[tid] += u;
        __syncthreads();
    }
    if (tid < NCHUNKS) csum[tid] = t[tid] - v;
}

__global__ __launch_bounds__(256) void bin_edges(const int* __restrict__ erow,
                                                 const int* __restrict__ ecol,
                                                 const float* __restrict__ eval,
                                                 const int* __restrict__ hist_all,
                                                 const int* __restrict__ csum,
                                                 uint2* __restrict__ bin) {
    __shared__ int hist[256];
    __shared__ int scnt[256];
    __shared__ int delta[256];
    __shared__ uint2 rec[BIN_TILE];
    const int tid = threadIdx.x;
    const int base = blockIdx.x * BIN_TILE;

    hist[tid] = 0;
    __syncthreads();

    int r[8]; unsigned pk[8];
#pragma unroll
    for (int j = 0; j < 8; ++j) {
        int e = base + j * 256 + tid;
        if (e < N_EDGES) {
            r[j] = erow[e];
            pk[j] = (((unsigned)ecol[e]) << 15) | (f2bf(eval[e]) & 0x7FFFu);
            atomicAdd(&hist[r[j] >> CHUNK_SHIFT], 1);
        } else {
            r[j] = -1;
        }
    }
    __syncthreads();

    const int cntb = hist[tid];
    for (int off = 1; off < 256; off <<= 1) {
        int u = 0;
        if (tid >= off) u = hist[tid - off];
        __syncthreads();
        if (tid >= off) hist[tid] += u;
        __syncthreads();
    }
    const int excl = hist[tid] - cntb;
    if (tid < NCHUNKS)
        delta[tid] = csum[tid] + hist_all[blockIdx.x * PADC + tid] - excl;
    scnt[tid] = 0;
    __syncthreads();

#pragma unroll
    for (int j = 0; j < 8; ++j) {
        if (r[j] >= 0) {
            int b = r[j] >> CHUNK_SHIFT;
            int s = (b ? hist[b - 1] : 0) + atomicAdd(&scnt[b], 1);
            rec[s] = make_uint2(pk[j], (unsigned)r[j]);
        }
    }
    __syncthreads();

    const int n = min(BIN_TILE, N_EDGES - base);
    for (int s = tid; s < n; s += 256) {
        uint2 q = rec[s];
        bin[delta[(int)q.y >> CHUNK_SHIFT] + s] = q;
    }
}

// 1024 threads (was 512): doubles per-CU wave count during the 196-block
// phase (0.77 blocks/CU -> machine 3/4 idle was the defect). Structure same.
__global__ __launch_bounds__(1024) void sort_chunk(const int* __restrict__ csum,
                                                   const uint2* __restrict__ bin,
                                                   int* __restrict__ row_ptr,
                                                   unsigned* __restrict__ cv) {
    __shared__ int h[CHUNK];
    const int b = blockIdx.x;
    const int tid = threadIdx.x;
    const int start = csum[b];
    const int end = (b + 1 < NCHUNKS) ? csum[b + 1] : N_EDGES;

    if (tid < CHUNK) h[tid] = 0;
    __syncthreads();
    {
        int i = start + tid;
        for (; i + 3 * 1024 < end; i += 4 * 1024) {
            int r0 = (int)bin[i].y, r1 = (int)bin[i + 1024].y;
            int r2 = (int)bin[i + 2048].y, r3 = (int)bin[i + 3072].y;
            atomicAdd(&h[r0 & (CHUNK - 1)], 1);
            atomicAdd(&h[r1 & (CHUNK - 1)], 1);
            atomicAdd(&h[r2 & (CHUNK - 1)], 1);
            atomicAdd(&h[r3 & (CHUNK - 1)], 1);
        }
        for (; i < end; i += 1024)
            atomicAdd(&h[(int)bin[i].y & (CHUNK - 1)], 1);
    }
    __syncthreads();

    const int cnt = (tid < CHUNK) ? h[tid] : 0;
    for (int off = 1; off < CHUNK; off <<= 1) {
        int u = 0;
        if (tid < CHUNK && tid >= off) u = h[tid - off];
        __syncthreads();
        if (tid < CHUNK && tid >= off) h[tid] += u;
        __syncthreads();
    }
    int rp = 0;
    if (tid < CHUNK) {
        rp = start + h[tid] - cnt;
        const int row = (b << CHUNK_SHIFT) + tid;
        if (row < N_NODES) row_ptr[row] = rp;
    }
    if (b == NCHUNKS - 1 && tid == 0) row_ptr[N_NODES] = N_EDGES;
    __syncthreads();
    if (tid < CHUNK) h[tid] = rp;
    __syncthreads();

    int i = start + tid;
    for (; i + 3 * 1024 < end; i += 4 * 1024) {
        uint2 q0 = bin[i], q1 = bin[i + 1024], q2 = bin[i + 2048], q3 = bin[i + 3072];
        int p0 = atomicAdd(&h[(int)q0.y & (CHUNK - 1)], 1);
        int p1 = atomicAdd(&h[(int)q1.y & (CHUNK - 1)], 1);
        int p2 = atomicAdd(&h[(int)q2.y & (CHUNK - 1)], 1);
        int p3 = atomicAdd(&h[(int)q3.y & (CHUNK - 1)], 1);
        cv[p0] = q0.x; cv[p1] = q1.x; cv[p2] = q2.x; cv[p3] = q3.x;
    }
    for (; i < end; i += 1024) {
        uint2 q = bin[i];
        int p = atomicAdd(&h[(int)q.y & (CHUNK - 1)], 1);
        cv[p] = q.x;
    }
}

// ---------------------------------------------------------------------------
// FUSED gather + GEMM, FB=16 / 256 threads (was 32/512): smaller co-schedule
// unit -> ~8 blocks/CU, restores the standalone gather's 77%+ occupancy
// (round-9 fused at 512thr dropped to 63% and cost ~+50us). Phase 1: 4 waves
// x 4 rows gather into 8.4 KB LDS. One barrier. Phase 2: per wave 1x4 MFMA
// fragments (cols wv*64..+63), B direct from L2.
// ---------------------------------------------------------------------------
#define FB 16
#define FLD 264   // LDS row stride in shorts

__global__ __launch_bounds__(256) void gather_gemm(
    const int* __restrict__ row_ptr,
    const unsigned* __restrict__ cv,
    const unsigned short* __restrict__ xh,
    const unsigned short* __restrict__ Bt,   // Wt bf16 [N][K] = [256][256]
    const float* __restrict__ bias,
    float* __restrict__ C)
{
    __shared__ unsigned short As[FB * FLD];   // 8448 B

    const int tid = threadIdx.x;
    const int lane = tid & 63;
    const int wv = tid >> 6;                  // 0..3
    const int block_m = blockIdx.x * FB;
    const uint2* __restrict__ x2 = (const uint2*)xh;

    // ---- phase 1: gather 4 rows per wave into As ----
#pragma unroll
    for (int rr = 0; rr < 4; ++rr) {
        const int rl = wv * 4 + rr;
        const int row = block_m + rl;
        const int start = row_ptr[row];
        const int deg = row_ptr[row + 1] - start;
        const unsigned* __restrict__ p = cv + start;

        float a0 = 0.f, a1 = 0.f, a2 = 0.f, a3 = 0.f;
        int i = 0;
        for (; i + 7 < deg; i += 8) {
            unsigned e[8]; uint2 g[8];
#pragma unroll
            for (int j = 0; j < 8; ++j) e[j] = p[i + j];
#pragma unroll
            for (int j = 0; j < 8; ++j) g[j] = x2[(size_t)(e[j] >> 15) * 64 + lane];
#pragma unroll
            for (int j = 0; j < 8; ++j) {
                float v = __uint_as_float((e[j] & 0x7FFFu) << 16);
                a0 = fmaf(v, __uint_as_float(g[j].x << 16), a0);
                a1 = fmaf(v, __uint_as_float(g[j].x & 0xFFFF0000u), a1);
                a2 = fmaf(v, __uint_as_float(g[j].y << 16), a2);
                a3 = fmaf(v, __uint_as_float(g[j].y & 0xFFFF0000u), a3);
            }
        }
        for (; i + 3 < deg; i += 4) {
            unsigned e[4]; uint2 g[4];
#pragma unroll
            for (int j = 0; j < 4; ++j) e[j] = p[i + j];
#pragma unroll
            for (int j = 0; j < 4; ++j) g[j] = x2[(size_t)(e[j] >> 15) * 64 + lane];
#pragma unroll
            for (int j = 0; j < 4; ++j) {
                float v = __uint_as_float((e[j] & 0x7FFFu) << 16);
                a0 = fmaf(v, __uint_as_float(g[j].x << 16), a0);
                a1 = fmaf(v, __uint_as_float(g[j].x & 0xFFFF0000u), a1);
                a2 = fmaf(v, __uint_as_float(g[j].y << 16), a2);
                a3 = fmaf(v, __uint_as_float(g[j].y & 0xFFFF0000u), a3);
            }
        }
        for (; i < deg; ++i) {
            unsigned e0 = p[i];
            uint2 g0 = x2[(size_t)(e0 >> 15) * 64 + lane];
            float v0 = __uint_as_float((e0 & 0x7FFFu) << 16);
            a0 = fmaf(v0, __uint_as_float(g0.x << 16), a0);
            a1 = fmaf(v0, __uint_as_float(g0.x & 0xFFFF0000u), a1);
            a2 = fmaf(v0, __uint_as_float(g0.y << 16), a2);
            a3 = fmaf(v0, __uint_as_float(g0.y & 0xFFFF0000u), a3);
        }
        ushort4 o = make_ushort4(f2bf(a0), f2bf(a1), f2bf(a2), f2bf(a3));
        *(ushort4*)&As[rl * FLD + lane * 4] = o;
    }
    __syncthreads();

    // ---- phase 2: MFMA 16x256, wave wv covers cols wv*64..+63 ----
    const int quad = lane >> 4;
    const int l16 = lane & 15;

    f32x4 acc[4];
#pragma unroll
    for (int j = 0; j < 4; ++j) acc[j] = {0.f, 0.f, 0.f, 0.f};

#pragma unroll
    for (int ks = 0; ks < 8; ++ks) {
        const int ko = ks * 32 + quad * 8;
        bf16x8 af = *(const bf16x8*)&As[l16 * FLD + ko];
        bf16x8 bfr[4];
#pragma unroll
        for (int j = 0; j < 4; ++j)
            bfr[j] = *(const bf16x8*)&Bt[(size_t)(wv * 64 + j * 16 + l16) * DFEAT + ko];
#pragma unroll
        for (int j = 0; j < 4; ++j)
            acc[j] = __builtin_amdgcn_mfma_f32_16x16x32_bf16(af, bfr[j], acc[j], 0, 0, 0);
    }

    // epilogue: bias + relu (N_NODES multiple of 16 -> no M guard)
#pragma unroll
    for (int j = 0; j < 4; ++j) {
        const int n = wv * 64 + j * 16 + l16;
        const float bj = bias[n];
        const int m0 = block_m + quad * 4;
#pragma unroll
        for (int rg = 0; rg < 4; ++rg) {
            const int m = m0 + rg;
            C[(size_t)m * UNITS + n] = fmaxf(acc[j][rg] + bj, 0.f);
        }
    }
}

extern "C" void kernel_launch(void* const* d_in, const int* in_sizes, int n_in,
                              void* d_out, int out_size, void* d_ws, size_t ws_size,
                              hipStream_t stream) {
    const int*   erow = (const int*)d_in[0];
    const int*   ecol = (const int*)d_in[1];
    const float* eval = (const float*)d_in[2];
    const float* x    = (const float*)d_in[3];
    const float* w    = (const float*)d_in[4];
    const float* bias = (const float*)d_in[5];
    float* out = (float*)d_out;

    // Workspace carve-up (xh in ws — fused kernel writes d_out while reading xh):
    //   xh bf16    : 51,200,000
    //   row_ptr    : 400,016   (N_NODES+1 ints)
    //   csum       : 1,024
    //   chunk_cnt  : 1,024
    //   cv (u32)   : 12,800,000
    //   Wt bf16    : 131,072
    //   bin (u64)  : 25,600,000
    //   hist_all   : 1563 x 208 x 4 = 1,300,416   total ~91.4 MB
    char* ws = (char*)d_ws;
    unsigned short* xh        = (unsigned short*)(ws);
    int*            row_ptr   = (int*)(ws + 51200000);
    int*            csum      = (int*)(ws + 51600016);
    int*            chunk_cnt = (int*)(ws + 51601040);
    unsigned*       cv        = (unsigned*)(ws + 51602064);
    unsigned short* wt        = (unsigned short*)(ws + 64402064);
    uint2*          bin       = (uint2*)(ws + 64533136);
    int*            hist_all  = (int*)(ws + 90133136);

    // converts + chunk_hist, one launch
    convert_hist<<<25000 + UNITS + BIN_NWG, 256, 0, stream>>>(
        (const float4*)x, xh, w, wt, erow, hist_all);

    // CSR build
    col_scan<<<NCHUNKS, 256, 0, stream>>>(hist_all, chunk_cnt);
    scan_chunks<<<1, 256, 0, stream>>>(chunk_cnt, csum);
    bin_edges<<<BIN_NWG, 256, 0, stream>>>(erow, ecol, eval, hist_all, csum, bin);
    sort_chunk<<<NCHUNKS, 1024, 0, stream>>>(csum, bin, row_ptr, cv);

    // fused: row gather (LDS) -> MFMA -> relu(+bias) -> out
    gather_gemm<<<N_NODES / FB, 256, 0, stream>>>(row_ptr, cv, xh, wt, bias, out);
}